// Round 8
// baseline (303.440 us; speedup 1.0000x reference)
//
#include <hip/hip_runtime.h>
#include <cstdint>

#define TT 50
#define II 5
#define PRED 12

typedef _Float16 f16;
typedef _Float16 f16x8 __attribute__((ext_vector_type(8)));
typedef float f32x4 __attribute__((ext_vector_type(4)));

__device__ __forceinline__ float fsig(float x) {
    return __builtin_amdgcn_rcpf(1.f + __builtin_amdgcn_exp2f(-1.4426950408889634f * x));
}
__device__ __forceinline__ float ftanh(float x) {
    return 1.f - 2.f * __builtin_amdgcn_rcpf(1.f + __builtin_amdgcn_exp2f(2.885390081777927f * x));
}

// Interleave request for a paired phase (VALU-finish gA || MFMA gB):
// per chunk {1 ds_read_b128, 4 MFMA, 22 VALU} x10 ~= the phase's real mix
// (10 DS_READ / 40 MFMA / ~220 VALU incl. 80 transcendentals). MFMA hazards
// on CDNA are software-managed, so a wave issues independent VALU while an
// MFMA is in flight -- this directive makes the scheduler emit that order.
__device__ __forceinline__ void sched_mix() {
    #pragma unroll
    for (int i = 0; i < 10; ++i) {
        __builtin_amdgcn_sched_group_barrier(0x100, 1, 0);   // DS_READ
        __builtin_amdgcn_sched_group_barrier(0x008, 4, 0);   // MFMA
        __builtin_amdgcn_sched_group_barrier(0x002, 22, 0);  // VALU
    }
}

// A-fragments: tile (w,gs) row r holds gate-row gw = gs*128 + w*16 + r.
// Lane (q,cl) element j of wr[gs][kc] = Wcat[gw(cl)][k = kc*32 + q*8 + j]:
//   kc<4 -> Whh[gw][k]; kc=4 (only q==0 nonzero): j<5 Wih[gw][j], j==5 bih+bhh, else 0.
// MFMA C layout (col=cl, row=q*4+idx) gives acc[gs][idx] = gate gs of unit
//   jb+idx (jb = w*16 + q*4), sample ns*16+cl.
__device__ __forceinline__ void load_frags(const float* __restrict__ Wih,
                                           const float* __restrict__ Whh,
                                           const float* __restrict__ bih,
                                           const float* __restrict__ bhh,
                                           int w, int q, int cl, f16x8 wr[4][5]) {
    #pragma unroll
    for (int gs = 0; gs < 4; ++gs) {
        const int gw = gs * 128 + w * 16 + cl;
        const float* whr = Whh + gw * 128 + q * 8;
        #pragma unroll
        for (int kc = 0; kc < 4; ++kc) {
            f32x4 a = *(const f32x4*)(whr + kc * 32);
            f32x4 b = *(const f32x4*)(whr + kc * 32 + 4);
            f16x8 f;
            f[0] = (f16)a[0]; f[1] = (f16)a[1]; f[2] = (f16)a[2]; f[3] = (f16)a[3];
            f[4] = (f16)b[0]; f[5] = (f16)b[1]; f[6] = (f16)b[2]; f[7] = (f16)b[3];
            wr[gs][kc] = f;
        }
        f16x8 f;
        #pragma unroll
        for (int j = 0; j < 8; ++j) f[j] = (f16)0.f;
        if (q == 0) {
            f[0] = (f16)Wih[gw * 5 + 0]; f[1] = (f16)Wih[gw * 5 + 1];
            f[2] = (f16)Wih[gw * 5 + 2]; f[3] = (f16)Wih[gw * 5 + 3];
            f[4] = (f16)Wih[gw * 5 + 4];
            f[5] = (f16)(bih[gw] + bhh[gw]);
        }
        wr[gs][4] = f;
    }
}

// Intrinsic MFMA (hazard-safe; accumulators in AGPRs).
__device__ __forceinline__ void mfma_group(f32x4 (&acc)[4][2],
        const unsigned char* hb, const f16* xrow,
        const f16x8 (&wr)[4][5],
        const int (&hro)[4], int cl) {
    const f32x4 z4 = {0.f, 0.f, 0.f, 0.f};
    #pragma unroll
    for (int ns = 0; ns < 2; ++ns) {
        const unsigned char* cb = hb + ns * 4096;
        f16x8 bx = *(const f16x8*)(xrow + (ns * 16 + cl) * 8);
        f16x8 b0 = *(const f16x8*)(cb + hro[0]);
        acc[0][ns] = __builtin_amdgcn_mfma_f32_16x16x32_f16(wr[0][0], b0, z4, 0, 0, 0);
        acc[1][ns] = __builtin_amdgcn_mfma_f32_16x16x32_f16(wr[1][0], b0, z4, 0, 0, 0);
        acc[2][ns] = __builtin_amdgcn_mfma_f32_16x16x32_f16(wr[2][0], b0, z4, 0, 0, 0);
        acc[3][ns] = __builtin_amdgcn_mfma_f32_16x16x32_f16(wr[3][0], b0, z4, 0, 0, 0);
        #pragma unroll
        for (int kc = 1; kc < 4; ++kc) {
            f16x8 bh = *(const f16x8*)(cb + hro[kc]);
            acc[0][ns] = __builtin_amdgcn_mfma_f32_16x16x32_f16(wr[0][kc], bh, acc[0][ns], 0, 0, 0);
            acc[1][ns] = __builtin_amdgcn_mfma_f32_16x16x32_f16(wr[1][kc], bh, acc[1][ns], 0, 0, 0);
            acc[2][ns] = __builtin_amdgcn_mfma_f32_16x16x32_f16(wr[2][kc], bh, acc[2][ns], 0, 0, 0);
            acc[3][ns] = __builtin_amdgcn_mfma_f32_16x16x32_f16(wr[3][kc], bh, acc[3][ns], 0, 0, 0);
        }
        acc[0][ns] = __builtin_amdgcn_mfma_f32_16x16x32_f16(wr[0][4], bx, acc[0][ns], 0, 0, 0);
        acc[1][ns] = __builtin_amdgcn_mfma_f32_16x16x32_f16(wr[1][4], bx, acc[1][ns], 0, 0, 0);
        acc[2][ns] = __builtin_amdgcn_mfma_f32_16x16x32_f16(wr[2][4], bx, acc[2][ns], 0, 0, 0);
        acc[3][ns] = __builtin_amdgcn_mfma_f32_16x16x32_f16(wr[3][4], bx, acc[3][ns], 0, 0, 0);
    }
}

__device__ __forceinline__ void valu_enc(f32x4 (&acc)[4][2], float (&cr)[2][4],
        unsigned char* hb, int hwo) {
    #pragma unroll
    for (int ns = 0; ns < 2; ++ns) {
        union { f16 h[4]; uint2 u; } pk;
        #pragma unroll
        for (int idx = 0; idx < 4; ++idx) {
            float ii = fsig(acc[0][ns][idx]);
            float ff = fsig(acc[1][ns][idx]);
            float gg = ftanh(acc[2][ns][idx]);
            float oo = fsig(acc[3][ns][idx]);
            float cn = ff * cr[ns][idx] + ii * gg;
            cr[ns][idx] = cn;
            pk.h[idx] = (f16)(oo * ftanh(cn));
        }
        *(uint2*)(hb + ns * 4096 + hwo) = pk.u;
    }
}

__device__ __forceinline__ void valu_dec(f32x4 (&acc)[4][2], float (&cr)[2][4],
        unsigned char* hb, int hwo,
        const f16 (&w0h)[4], const f16 (&w1h)[4],
        float (*pp)[32][2], int w, int q, int cl) {
    #pragma unroll
    for (int ns = 0; ns < 2; ++ns) {
        union { f16 h[4]; uint2 u; } pk;
        float p0 = 0.f, p1 = 0.f;
        #pragma unroll
        for (int idx = 0; idx < 4; ++idx) {
            float ii = fsig(acc[0][ns][idx]);
            float ff = fsig(acc[1][ns][idx]);
            float gg = ftanh(acc[2][ns][idx]);
            float oo = fsig(acc[3][ns][idx]);
            float cn = ff * cr[ns][idx] + ii * gg;
            cr[ns][idx] = cn;
            float hv = oo * ftanh(cn);
            p0 += hv * (float)w0h[idx];
            p1 += hv * (float)w1h[idx];
            pk.h[idx] = (f16)hv;
        }
        *(uint2*)(hb + ns * 4096 + hwo) = pk.u;
        p0 += __shfl_xor(p0, 16); p0 += __shfl_xor(p0, 32);
        p1 += __shfl_xor(p1, 16); p1 += __shfl_xor(p1, 32);
        if (q == 0) { pp[w][ns * 16 + cl][0] = p0; pp[w][ns * 16 + cl][1] = p1; }
    }
}

__device__ __forceinline__ void finalize(int g, int tdf, int tid, int s0,
        const float (*pp)[32][2], float lb0, float lb1,
        f16* xstage, float* __restrict__ out) {
    if (tid < 32) {
        float a0 = lb0, a1 = lb1;
        #pragma unroll
        for (int ww = 0; ww < 8; ++ww) { a0 += pp[ww][tid][0]; a1 += pp[ww][tid][1]; }
        const int s = g * 32 + tid;
        float2 o2; o2.x = a0; o2.y = a1;
        *(float2*)(out + (size_t)(s0 + s) * (PRED * 2) + tdf * 2) = o2;
        if (tdf < PRED - 1) {
            uint4 row = *(const uint4*)(xstage + (49 * 64 + s) * 8);
            union { f16 h[2]; uint32_t u; } pk2;
            pk2.h[0] = (f16)a0; pk2.h[1] = (f16)a1;
            row.x = pk2.u;
            *(uint4*)(xstage + ((50 + g) * 64 + s) * 8) = row;
        }
    }
}

// 256 blocks x 512 threads, 64 samples/block as TWO pipeline groups of 32.
// Each phase: VALU-finish(gA) || MFMA(gB), now with a forced instruction-level
// interleave (sched_mix) so the MFMA pipe runs under the transcendental block.
__global__ __launch_bounds__(512, 2)
void lstm_kernel(const float* __restrict__ x,
                 const float* __restrict__ eWih, const float* __restrict__ eWhh,
                 const float* __restrict__ ebih, const float* __restrict__ ebhh,
                 const float* __restrict__ dWih, const float* __restrict__ dWhh,
                 const float* __restrict__ dbih, const float* __restrict__ dbhh,
                 const float* __restrict__ linW, const float* __restrict__ linB,
                 float* __restrict__ out) {
    __shared__ __align__(16) unsigned char hstate[2 * 8192];
    __shared__ __align__(16) f16 xstage[52 * 64 * 8];
    __shared__ float predpart[2][8][32][2];

    const int tid  = threadIdx.x;
    const int lane = tid & 63;
    const int w    = tid >> 6;
    const int q    = lane >> 4;
    const int cl   = lane & 15;
    const int s0   = blockIdx.x * 64;
    const int jb   = w * 16 + q * 4;
    const int fswz = (2 * (cl & 7)) | (cl >> 3);

    int hro[4];
    #pragma unroll
    for (int kc = 0; kc < 4; ++kc)
        hro[kc] = cl * 256 + (((kc * 4 + q) ^ fswz) & 15) * 16;
    const int physh = ((jb >> 3) ^ fswz) & 15;
    const int hwo   = cl * 256 + physh * 16 + (jb & 7) * 2;

    {
        uint32_t* sp = (uint32_t*)hstate;
        #pragma unroll
        for (int r = 0; r < 8; ++r) sp[tid + r * 512] = 0u;
    }
    #pragma unroll
    for (int k = 0; k < 7; ++k) {
        int c = tid + k * 512;
        if (c < TT * 64) {
            int t = c >> 6, s = c & 63;
            const float* xr = x + (size_t)(s0 + s) * (TT * II) + t * II;
            union { f16 h[8]; uint4 u; } pk;
            pk.h[0] = (f16)xr[0]; pk.h[1] = (f16)xr[1]; pk.h[2] = (f16)xr[2];
            pk.h[3] = (f16)xr[3]; pk.h[4] = (f16)xr[4];
            pk.h[5] = (f16)1.f;  pk.h[6] = (f16)0.f;  pk.h[7] = (f16)0.f;
            *(uint4*)(xstage + (t * 64 + s) * 8) = pk.u;
        }
    }

    f16x8 wr[4][5];
    load_frags(eWih, eWhh, ebih, ebhh, w, q, cl, wr);

    float creg0[2][4], creg1[2][4];
    #pragma unroll
    for (int ns = 0; ns < 2; ++ns)
        #pragma unroll
        for (int i = 0; i < 4; ++i) { creg0[ns][i] = 0.f; creg1[ns][i] = 0.f; }

    f32x4 accA[4][2], accB[4][2];
    unsigned char* hb0 = hstate;
    unsigned char* hb1 = hstate + 8192;

    __syncthreads();

    // ===================== encoder pipeline =====================
    mfma_group(accA, hb0, xstage + 0, wr, hro, cl);
    __syncthreads();
    #pragma unroll 1
    for (int j = 0; j < 49; ++j) {
        valu_enc(accA, creg0, hb0, hwo);
        mfma_group(accB, hb1, xstage + (j * 64 + 32) * 8, wr, hro, cl);
        sched_mix();
        __syncthreads();
        valu_enc(accB, creg1, hb1, hwo);
        mfma_group(accA, hb0, xstage + ((j + 1) * 64) * 8, wr, hro, cl);
        sched_mix();
        __syncthreads();
    }
    valu_enc(accA, creg0, hb0, hwo);
    mfma_group(accB, hb1, xstage + (49 * 64 + 32) * 8, wr, hro, cl);
    sched_mix();
    __syncthreads();
    valu_enc(accB, creg1, hb1, hwo);
    __syncthreads();

    // ---- decoder weights + lin/bias ----
    load_frags(dWih, dWhh, dbih, dbhh, w, q, cl, wr);
    f16 w0h[4], w1h[4];
    #pragma unroll
    for (int idx = 0; idx < 4; ++idx) {
        w0h[idx] = (f16)linW[jb + idx];
        w1h[idx] = (f16)linW[128 + jb + idx];
    }
    const float lb0 = linB[0], lb1 = linB[1];

    // ===================== decoder pipeline =====================
    mfma_group(accA, hb0, xstage + (49 * 64) * 8, wr, hro, cl);
    __syncthreads();
    valu_dec(accA, creg0, hb0, hwo, w0h, w1h, predpart[0], w, q, cl);
    mfma_group(accB, hb1, xstage + (49 * 64 + 32) * 8, wr, hro, cl);
    sched_mix();
    __syncthreads();
    #pragma unroll 1
    for (int td = 1; td <= 11; ++td) {
        finalize(0, td - 1, tid, s0, predpart[0], lb0, lb1, xstage, out);
        __syncthreads();
        valu_dec(accB, creg1, hb1, hwo, w0h, w1h, predpart[1], w, q, cl);
        mfma_group(accA, hb0, xstage + (50 * 64) * 8, wr, hro, cl);
        sched_mix();
        __syncthreads();
        finalize(1, td - 1, tid, s0, predpart[1], lb0, lb1, xstage, out);
        __syncthreads();
        valu_dec(accA, creg0, hb0, hwo, w0h, w1h, predpart[0], w, q, cl);
        mfma_group(accB, hb1, xstage + (51 * 64 + 32) * 8, wr, hro, cl);
        sched_mix();
        __syncthreads();
    }
    finalize(0, 11, tid, s0, predpart[0], lb0, lb1, xstage, out);
    __syncthreads();
    valu_dec(accB, creg1, hb1, hwo, w0h, w1h, predpart[1], w, q, cl);
    __syncthreads();
    finalize(1, 11, tid, s0, predpart[1], lb0, lb1, xstage, out);
}

extern "C" void kernel_launch(void* const* d_in, const int* in_sizes, int n_in,
                              void* d_out, int out_size, void* d_ws, size_t ws_size,
                              hipStream_t stream) {
    (void)in_sizes; (void)n_in; (void)out_size; (void)d_ws; (void)ws_size;
    const float* x    = (const float*)d_in[0];
    const float* eWih = (const float*)d_in[1];
    const float* eWhh = (const float*)d_in[2];
    const float* ebih = (const float*)d_in[3];
    const float* ebhh = (const float*)d_in[4];
    const float* dWih = (const float*)d_in[5];
    const float* dWhh = (const float*)d_in[6];
    const float* dbih = (const float*)d_in[7];
    const float* dbhh = (const float*)d_in[8];
    const float* linW = (const float*)d_in[9];
    const float* linB = (const float*)d_in[10];

    lstm_kernel<<<256, 512, 0, stream>>>(x, eWih, eWhh, ebih, ebhh,
                                         dWih, dWhh, dbih, dbhh,
                                         linW, linB, (float*)d_out);
}